// Round 1
// baseline (83.584 us; speedup 1.0000x reference)
//
#include <hip/hip_runtime.h>

#define T_LEN 768
#define TC 32                 // timesteps per chunk
#define NCH (T_LEN / TC)      // 24 chunks
#define RPB 32                // rows per block (block = 64 threads = 1 wave, 2 lanes/row)
#define SA 36                 // LDS stride for a/b planes (float4-aligned, padded)
#define SO 33                 // LDS stride for output plane (conflict-free scalar)

struct Params { const float* p[27]; };

__device__ __forceinline__ float ex2(float x) {
    float r; asm("v_exp_f32 %0, %1" : "=v"(r) : "v"(x)); return r;   // exp2(x), ~1 ulp
}
__device__ __forceinline__ float frcp(float x) {
    return __builtin_amdgcn_rcpf(x);                                  // 1/x, ~1 ulp
}

__global__ __launch_bounds__(64) void cell_kernel(Params P, float* __restrict__ out) {
    __shared__ float lds_a[RPB * SA];
    __shared__ float lds_b[RPB * SA];
    __shared__ float lds_o[RPB * SO];

    const int tid = (int)threadIdx.x;
    const int r0  = (int)blockIdx.x * RPB;
    const bool isX = (tid & 1) == 0;
    const int row = tid >> 1;

    const float* __restrict__ inp = P.p[0];
    const float capx = P.p[1][0], capy = P.p[2][0];
    const float g_ax = P.p[3][0],  m_ax = P.p[4][0],  s_ax = P.p[5][0],  q_ax = P.p[6][0];
    const float g_by = P.p[7][0],  m_by = P.p[8][0],  s_by = P.p[9][0],  q_by = P.p[10][0];
    const float g_xx = P.p[11][0], m_xx = P.p[12][0], s_xx = P.p[13][0], q_xx = P.p[14][0];
    const float g_xy = P.p[15][0], m_xy = P.p[16][0], s_xy = P.p[17][0], q_xy = P.p[18][0];
    const float g_yx = P.p[19][0], m_yx = P.p[20][0], s_yx = P.p[21][0], q_yx = P.p[22][0];
    const float g_yy = P.p[23][0], m_yy = P.p[24][0], s_yy = P.p[25][0], q_yy = P.p[26][0];

    const float icx = 1.0f / capx, icy = 1.0f / capy;
    const float L2E = 1.44269504088896340736f;

    // Role-specialized constants.
    // Even lane (X): in-syn = ax (pre=a), self-syn = xx (pre=x), cross-out = xy (pre=x -> y).
    // Odd lane  (Y): in-syn = by (pre=b), self-syn = yy (pre=y), cross-out = yx (pre=y -> x).
    const float k1 = (isX ? s_ax : s_by) * L2E;
    const float c1 = k1 * (isX ? m_ax : m_by);
    const float k2 = (isX ? s_xx : s_yy) * L2E;
    const float c2 = k2 * (isX ? m_xx : m_yy);
    const float k3 = (isX ? s_xy : s_yx) * L2E;
    const float c3 = k3 * (isX ? m_xy : m_yx);
    const float ico = isX ? icx : icy;   // own-channel 1/C
    const float icc = isX ? icy : icx;   // other-channel 1/C (for cross-out partials)
    const float A1 = (isX ? g_ax * q_ax : g_by * q_by) * ico;
    const float G1 = (isX ? g_ax : g_by) * ico;
    const float A2 = (isX ? g_xx * q_xx : g_yy * q_yy) * ico;
    const float G2 = (isX ? g_xx : g_yy) * ico;
    const float A3 = (isX ? g_xy * q_xy : g_yx * q_yx) * icc;
    const float G3 = (isX ? g_xy : g_yx) * icc;

    const float4* __restrict__ in4 = (const float4*)inp;   // row stride = 768*2/4 = 384

    float v = 0.0f;            // own state (x for even lanes, y for odd lanes)
    float4 bufA[8], bufB[8];

    auto LOAD = [&](float4 (&buf)[8], int c) {
        #pragma unroll
        for (int k = 0; k < 8; ++k) {
            int idx = tid + 64 * k;            // 512 float4 = 32 rows x 16
            int r = idx >> 4, q = idx & 15;    // 16 consecutive lanes stream one row (256B)
            buf[k] = in4[(size_t)(r0 + r) * 384 + c * 16 + q];
        }
    };
    auto STAGE = [&](float4 (&buf)[8]) {       // deinterleave (a,b,a,b) -> a-plane / b-plane
        #pragma unroll
        for (int k = 0; k < 8; ++k) {
            int idx = tid + 64 * k;
            int r = idx >> 4, q = idx & 15;
            int tp = q << 1;
            lds_a[r * SA + tp]     = buf[k].x;
            lds_b[r * SA + tp]     = buf[k].y;
            lds_a[r * SA + tp + 1] = buf[k].z;
            lds_b[r * SA + tp + 1] = buf[k].w;
        }
    };
    const float* myplane = isX ? lds_a : lds_b;

    auto COMPUTE = [&](int c) {
        // Pull this lane's 32 input values for the chunk into registers.
        float4 rv[8];
        #pragma unroll
        for (int j = 0; j < 8; ++j)
            rv[j] = *(const float4*)&myplane[row * SA + 4 * j];

        #pragma unroll
        for (int t = 0; t < TC; ++t) {
            float inv = ((const float*)&rv[t >> 2])[t & 3];
            float z1 = __builtin_fmaf(-k1, inv, c1);
            float z2 = __builtin_fmaf(-k2, v,   c2);
            float z3 = __builtin_fmaf(-k3, v,   c3);
            float s1 = frcp(1.0f + ex2(z1));
            float s2 = frcp(1.0f + ex2(z2));
            float s3 = frcp(1.0f + ex2(z3));
            float nl = __builtin_fmaf(A2, s2, A1 * s1);   // own num partial
            float dl = __builtin_fmaf(G2, s2, G1 * s1);   // own den partial
            float no = A3 * s3;                           // cross num -> partner
            float dko = G3 * s3;                          // cross den -> partner
            float nr = __shfl_xor(no, 1, 64);
            float dr = __shfl_xor(dko, 1, 64);
            float n = nl + nr;
            float d = dl + dr;
            v = __builtin_fmaf(-v, d, v + n);             // v' = v + n - v*d
            if (isX) lds_o[row * SO + t] = v;             // stage x output
        }
        // Coalesced writeout: 256 float4 = 32 rows x 8, 8 lanes stream one row (128B).
        #pragma unroll
        for (int k = 0; k < 4; ++k) {
            int f = tid + 64 * k;
            int r = f >> 3, p = f & 7;
            float4 o;
            o.x = lds_o[r * SO + 4 * p + 0];
            o.y = lds_o[r * SO + 4 * p + 1];
            o.z = lds_o[r * SO + 4 * p + 2];
            o.w = lds_o[r * SO + 4 * p + 3];
            *(float4*)&out[(size_t)(r0 + r) * T_LEN + c * TC + 4 * p] = o;
        }
    };

    LOAD(bufA, 0);
    for (int cc = 0; cc < NCH; cc += 2) {
        STAGE(bufA);
        if (cc + 1 < NCH) LOAD(bufB, cc + 1);   // prefetch hides HBM latency under compute
        COMPUTE(cc);
        STAGE(bufB);
        if (cc + 2 < NCH) LOAD(bufA, cc + 2);
        COMPUTE(cc + 1);
    }
}

extern "C" void kernel_launch(void* const* d_in, const int* in_sizes, int n_in,
                              void* d_out, int out_size, void* d_ws, size_t ws_size,
                              hipStream_t stream) {
    (void)d_ws; (void)ws_size; (void)out_size; (void)n_in;
    Params P;
    for (int i = 0; i < 27; ++i) P.p[i] = (const float*)d_in[i];
    float* out = (float*)d_out;
    const int B = in_sizes[0] / (T_LEN * 2);   // 16384
    dim3 grid(B / RPB);                        // 512 blocks x 64 threads = 2 waves/CU
    cell_kernel<<<grid, dim3(64), 0, stream>>>(P, out);
}

// Round 2
// 71.655 us; speedup vs baseline: 1.1665x; 1.1665x over previous
//
#include <hip/hip_runtime.h>

#define T_LEN 768
#define TC 32                 // timesteps per chunk
#define NCH (T_LEN / TC)      // 24 chunks (even)
#define RPB 32                // rows per block (64 threads = 1 wave, 2 lanes/row)
#define SO 66                 // LDS output-plane stride (2-way write, spread reads)

struct Params { const float* p[27]; };

__device__ __forceinline__ float ex2(float x) {
    float r; asm("v_exp_f32 %0, %1" : "=v"(r) : "v"(x)); return r;   // exp2(x)
}
__device__ __forceinline__ float frcp(float x) {
    return __builtin_amdgcn_rcpf(x);                                  // 1/x
}

// SHARE=true: self-synapse sigmoid (xx/yy) also serves the cross-synapse
// (xy/yx) because std & mean match -> bitwise-identical math, 2 exp + 2 rcp
// per lane-step instead of 3+3. SHARE=false is the general fallback.
template<bool SHARE>
__device__ __forceinline__ void run_all(
    const float4* __restrict__ rowp4, float* __restrict__ out,
    float (*lds_o)[SO], int tid, int r0, bool isX,
    float k1, float c1, float k2, float c2, float k3, float c3,
    float A1, float G1, float A2, float G2, float A3, float G3)
{
    float v = 0.0f;                 // own state (x for even lanes, y for odd)
    float4 bufA[16], bufB[16];      // register double-buffer: 32 timesteps (a,b)

    auto LOAD = [&](float4 (&b)[16], int c) {
        #pragma unroll
        for (int j = 0; j < 16; ++j) b[j] = rowp4[c * 16 + j];
    };

    auto COMPUTE = [&](float4 (&b)[16], int c) {
        #pragma unroll
        for (int t = 0; t < TC; ++t) {
            float4 q = b[t >> 1];                  // compile-time reg select
            float va = (t & 1) ? q.z : q.x;        // a_t
            float vb = (t & 1) ? q.w : q.y;        // b_t
            float inv = isX ? va : vb;             // one v_cndmask

            float z1 = __builtin_fmaf(-k1, inv, c1);   // input synapse
            float e1 = ex2(z1);
            float r1 = frcp(1.0f + e1);
            float z2 = __builtin_fmaf(-k2, v, c2);     // self synapse (serial)
            float e2 = ex2(z2);
            float r2 = frcp(1.0f + e2);
            float r3;
            if (SHARE) {
                r3 = r2;                               // shared sigmoid
            } else {
                float z3 = __builtin_fmaf(-k3, v, c3);
                r3 = frcp(1.0f + ex2(z3));
            }
            float nl = __builtin_fmaf(A2, r2, A1 * r1);  // own numerator part
            float dl = __builtin_fmaf(G2, r2, G1 * r1);  // own denom part
            float nc = A3 * r3;                          // cross-out -> partner
            float dc = G3 * r3;
            float nr = __shfl_xor(nc, 1, 64);            // DPP quad_perm
            float dr = __shfl_xor(dc, 1, 64);
            float n = nl + nr;
            float d = dl + dr;
            v = __builtin_fmaf(-v, d, v + n);            // v' = v + n - v*d
            lds_o[t][tid] = v;                           // all lanes store
        }
        // Coalesced writeout: 256 float4 = 32 rows x 8; x lives in even cols.
        #pragma unroll
        for (int k = 0; k < 4; ++k) {
            int f = tid + 64 * k;
            int r = f >> 3, p = f & 7;
            float4 o;
            o.x = lds_o[4 * p + 0][2 * r];
            o.y = lds_o[4 * p + 1][2 * r];
            o.z = lds_o[4 * p + 2][2 * r];
            o.w = lds_o[4 * p + 3][2 * r];
            *(float4*)&out[(size_t)(r0 + r) * T_LEN + c * TC + 4 * p] = o;
        }
    };

    LOAD(bufA, 0);
    for (int cc = 0; cc < NCH; cc += 2) {
        LOAD(bufB, cc + 1);                 // prefetch next chunk (regs)
        COMPUTE(bufA, cc);
        if (cc + 2 < NCH) LOAD(bufA, cc + 2);
        COMPUTE(bufB, cc + 1);
    }
}

__global__ __launch_bounds__(64) void cell_kernel(Params P, float* __restrict__ out) {
    __shared__ float lds_o[TC][SO];

    const int tid = (int)threadIdx.x;
    const int r0  = (int)blockIdx.x * RPB;
    const bool isX = (tid & 1) == 0;
    const int row = tid >> 1;

    const float* __restrict__ inp = P.p[0];
    const float capx = P.p[1][0], capy = P.p[2][0];
    const float g_ax = P.p[3][0],  m_ax = P.p[4][0],  s_ax = P.p[5][0],  q_ax = P.p[6][0];
    const float g_by = P.p[7][0],  m_by = P.p[8][0],  s_by = P.p[9][0],  q_by = P.p[10][0];
    const float g_xx = P.p[11][0], m_xx = P.p[12][0], s_xx = P.p[13][0], q_xx = P.p[14][0];
    const float g_xy = P.p[15][0], m_xy = P.p[16][0], s_xy = P.p[17][0], q_xy = P.p[18][0];
    const float g_yx = P.p[19][0], m_yx = P.p[20][0], s_yx = P.p[21][0], q_yx = P.p[22][0];
    const float g_yy = P.p[23][0], m_yy = P.p[24][0], s_yy = P.p[25][0], q_yy = P.p[26][0];

    const float icx = 1.0f / capx, icy = 1.0f / capy;
    const float L2E = 1.44269504088896340736f;

    // Even lane (X): input-syn = ax (pre=a), self = xx (pre=x), cross-out = xy.
    // Odd lane  (Y): input-syn = by (pre=b), self = yy (pre=y), cross-out = yx.
    const float k1 = (isX ? s_ax : s_by) * L2E;
    const float c1 = k1 * (isX ? m_ax : m_by);
    const float k2 = (isX ? s_xx : s_yy) * L2E;
    const float c2 = k2 * (isX ? m_xx : m_yy);
    const float k3 = (isX ? s_xy : s_yx) * L2E;
    const float c3 = k3 * (isX ? m_xy : m_yx);
    const float ico = isX ? icx : icy;
    const float icc = isX ? icy : icx;
    const float A1 = (isX ? g_ax * q_ax : g_by * q_by) * ico;
    const float G1 = (isX ? g_ax : g_by) * ico;
    const float A2 = (isX ? g_xx * q_xx : g_yy * q_yy) * ico;
    const float G2 = (isX ? g_xx : g_yy) * ico;
    const float A3 = (isX ? g_xy * q_xy : g_yx * q_yx) * icc;
    const float G3 = (isX ? g_xy : g_yx) * icc;

    // Sigmoid sharing is valid when std & mean match for self vs cross synapse
    // on BOTH channels (uniform condition across the wave).
    const bool shareX = (s_xx == s_xy) && (m_xx == m_xy);
    const bool shareY = (s_yy == s_yx) && (m_yy == m_yx);

    const float4* __restrict__ rowp4 =
        (const float4*)inp + (size_t)(r0 + row) * (T_LEN * 2 / 4);   // 384 f4/row

    if (shareX && shareY)
        run_all<true >(rowp4, out, lds_o, tid, r0, isX, k1, c1, k2, c2, k3, c3,
                       A1, G1, A2, G2, A3, G3);
    else
        run_all<false>(rowp4, out, lds_o, tid, r0, isX, k1, c1, k2, c2, k3, c3,
                       A1, G1, A2, G2, A3, G3);
}

extern "C" void kernel_launch(void* const* d_in, const int* in_sizes, int n_in,
                              void* d_out, int out_size, void* d_ws, size_t ws_size,
                              hipStream_t stream) {
    (void)d_ws; (void)ws_size; (void)out_size; (void)n_in;
    Params P;
    for (int i = 0; i < 27; ++i) P.p[i] = (const float*)d_in[i];
    float* out = (float*)d_out;
    const int B = in_sizes[0] / (T_LEN * 2);   // 16384
    dim3 grid(B / RPB);                        // 512 blocks x 64 threads
    cell_kernel<<<grid, dim3(64), 0, stream>>>(P, out);
}

// Round 3
// 49.246 us; speedup vs baseline: 1.6973x; 1.4550x over previous
//
#include <hip/hip_runtime.h>

#define T_LEN 768
#define TC 32                 // timesteps per chunk
#define NCH (T_LEN / TC)      // 24 chunks (even)
#define RPB 32                // rows per block (64 threads = 1 wave, 2 lanes/row)
#define SO 66                 // LDS output-plane stride

struct Params { const float* p[27]; };

__device__ __forceinline__ float ex2(float x) {
    float r; asm("v_exp_f32 %0, %1" : "=v"(r) : "v"(x)); return r;   // exp2(x)
}
__device__ __forceinline__ float frcp(float x) {
    return __builtin_amdgcn_rcpf(x);                                  // 1/x
}
__device__ __forceinline__ float dpp_xor1(float x) {
    // lane <-> lane^1 swap via DPP quad_perm [1,0,3,2]; pure VALU, no LDS.
    return __int_as_float(
        __builtin_amdgcn_mov_dpp(__float_as_int(x), 0xB1, 0xF, 0xF, true));
}

// Each lane owns ONE channel of a row (even lane = x, odd = y) and per step:
//   v' = v + r1*(A1 - v*G1) + r2*(A2 - v*G2) + r2p*(A3 - v*G3)
// where r1 = sigmoid(input), r2 = sigmoid(own state), r2p = partner's
// cross-synapse sigmoid (received via ONE dpp swap).
// SHARE=true: cross-out sigmoid == self sigmoid (std/mean match), so the
// exchanged value is just r2 (saves one exp+add+rcp per step).
template<bool SHARE>
__device__ __forceinline__ void run_all(
    const float4* __restrict__ rowp4, float* __restrict__ out,
    float (*lds_o)[SO], int tid, int r0, bool isX,
    float k1, float c1, float k2, float c2, float k3, float c3,
    float A1, float G1, float A2, float G2, float A3, float G3)
{
    float v = 0.0f;                 // own state
    float4 bufA[16], bufB[16];      // register double-buffer: 32 steps of (a,b)

    auto LOAD = [&](float4 (&b)[16], int c) {
        #pragma unroll
        for (int j = 0; j < 16; ++j) b[j] = rowp4[c * 16 + j];
    };

    auto COMPUTE = [&](float4 (&b)[16], int c) {
        // Batch the state-independent input sigmoids: pure ILP that fills
        // issue slots while the serial loop stalls on exp/rcp latency.
        float r1[TC];
        #pragma unroll
        for (int t = 0; t < TC; ++t) {
            float4 q = b[t >> 1];
            float va = (t & 1) ? q.z : q.x;
            float vb = (t & 1) ? q.w : q.y;
            float inv = isX ? va : vb;
            r1[t] = frcp(1.0f + ex2(__builtin_fmaf(-k1, inv, c1)));
        }
        // Serial recurrence: chain = fma -> exp -> add -> rcp -> dpp -> fma.
        #pragma unroll
        for (int t = 0; t < TC; ++t) {
            float e2 = ex2(__builtin_fmaf(-k2, v, c2));
            float r2 = frcp(1.0f + e2);
            float rx;
            if (SHARE) rx = r2;
            else       rx = frcp(1.0f + ex2(__builtin_fmaf(-k3, v, c3)));
            float rp = dpp_xor1(rx);                    // partner's sigmoid
            float u1 = __builtin_fmaf(-v, G1, A1);      // independent of exp
            float u2 = __builtin_fmaf(-v, G2, A2);
            float u3 = __builtin_fmaf(-v, G3, A3);
            v = __builtin_fmaf(u3, rp,
                __builtin_fmaf(u2, r2,
                __builtin_fmaf(u1, r1[t], v)));
            lds_o[t][tid] = v;
        }
        // Coalesced writeout: 256 float4 = 32 rows x 8; x lives in even cols.
        #pragma unroll
        for (int k = 0; k < 4; ++k) {
            int f = tid + 64 * k;
            int r = f >> 3, p = f & 7;
            float4 o;
            o.x = lds_o[4 * p + 0][2 * r];
            o.y = lds_o[4 * p + 1][2 * r];
            o.z = lds_o[4 * p + 2][2 * r];
            o.w = lds_o[4 * p + 3][2 * r];
            *(float4*)&out[(size_t)(r0 + r) * T_LEN + c * TC + 4 * p] = o;
        }
    };

    LOAD(bufA, 0);
    for (int cc = 0; cc < NCH; cc += 2) {
        LOAD(bufB, cc + 1);                 // prefetch next chunk (regs)
        COMPUTE(bufA, cc);
        if (cc + 2 < NCH) LOAD(bufA, cc + 2);
        COMPUTE(bufB, cc + 1);
    }
}

__global__ __launch_bounds__(64) void cell_kernel(Params P, float* __restrict__ out) {
    __shared__ float lds_o[TC][SO];

    const int tid = (int)threadIdx.x;
    const int r0  = (int)blockIdx.x * RPB;
    const bool isX = (tid & 1) == 0;
    const int row = tid >> 1;

    const float* __restrict__ inp = P.p[0];
    const float capx = P.p[1][0], capy = P.p[2][0];
    const float g_ax = P.p[3][0],  m_ax = P.p[4][0],  s_ax = P.p[5][0],  q_ax = P.p[6][0];
    const float g_by = P.p[7][0],  m_by = P.p[8][0],  s_by = P.p[9][0],  q_by = P.p[10][0];
    const float g_xx = P.p[11][0], m_xx = P.p[12][0], s_xx = P.p[13][0], q_xx = P.p[14][0];
    const float g_xy = P.p[15][0], m_xy = P.p[16][0], s_xy = P.p[17][0], q_xy = P.p[18][0];
    const float g_yx = P.p[19][0], m_yx = P.p[20][0], s_yx = P.p[21][0], q_yx = P.p[22][0];
    const float g_yy = P.p[23][0], m_yy = P.p[24][0], s_yy = P.p[25][0], q_yy = P.p[26][0];

    const float icx = 1.0f / capx, icy = 1.0f / capy;
    const float L2E = 1.44269504088896340736f;

    // Even lane (X): input-syn ax (pre=a), self xx (pre=x), cross-IN yx (pre=y),
    //                cross-OUT sigmoid params xy (pre=x, sent to partner).
    // Odd lane  (Y): input-syn by, self yy, cross-IN xy, cross-OUT params yx.
    const float k1 = (isX ? s_ax : s_by) * L2E;
    const float c1 = k1 * (isX ? m_ax : m_by);
    const float k2 = (isX ? s_xx : s_yy) * L2E;
    const float c2 = k2 * (isX ? m_xx : m_yy);
    const float k3 = (isX ? s_xy : s_yx) * L2E;      // own-state cross-OUT sigmoid
    const float c3 = k3 * (isX ? m_xy : m_yx);
    const float ico = isX ? icx : icy;
    const float A1 = (isX ? g_ax * q_ax : g_by * q_by) * ico;
    const float G1 = (isX ? g_ax : g_by) * ico;
    const float A2 = (isX ? g_xx * q_xx : g_yy * q_yy) * ico;
    const float G2 = (isX ? g_xx : g_yy) * ico;
    const float A3 = (isX ? g_yx * q_yx : g_xy * q_xy) * ico;   // cross-IN
    const float G3 = (isX ? g_yx : g_xy) * ico;

    // Sharing valid when the cross-out sigmoid params equal the self params
    // on BOTH channels (uniform across the wave).
    const bool shareX = (s_xx == s_xy) && (m_xx == m_xy);
    const bool shareY = (s_yy == s_yx) && (m_yy == m_yx);

    const float4* __restrict__ rowp4 =
        (const float4*)inp + (size_t)(r0 + row) * (T_LEN * 2 / 4);   // 384 f4/row

    if (shareX && shareY)
        run_all<true >(rowp4, out, lds_o, tid, r0, isX, k1, c1, k2, c2, k3, c3,
                       A1, G1, A2, G2, A3, G3);
    else
        run_all<false>(rowp4, out, lds_o, tid, r0, isX, k1, c1, k2, c2, k3, c3,
                       A1, G1, A2, G2, A3, G3);
}

extern "C" void kernel_launch(void* const* d_in, const int* in_sizes, int n_in,
                              void* d_out, int out_size, void* d_ws, size_t ws_size,
                              hipStream_t stream) {
    (void)d_ws; (void)ws_size; (void)out_size; (void)n_in;
    Params P;
    for (int i = 0; i < 27; ++i) P.p[i] = (const float*)d_in[i];
    float* out = (float*)d_out;
    const int B = in_sizes[0] / (T_LEN * 2);   // 16384
    dim3 grid(B / RPB);                        // 512 blocks x 64 threads
    cell_kernel<<<grid, dim3(64), 0, stream>>>(P, out);
}